// Round 1
// baseline (2602.901 us; speedup 1.0000x reference)
//
#include <hip/hip_runtime.h>
#include <stdint.h>

#define BB 64
#define TT 512
#define DD 256
#define HH 512
#define NG 2048
#define BT (BB*TT)
#define NCLS 1000

typedef _Float16 f16;
typedef _Float16 f16x2 __attribute__((ext_vector_type(2)));
typedef _Float16 f16x4 __attribute__((ext_vector_type(4)));
typedef _Float16 f16x8 __attribute__((ext_vector_type(8)));
typedef float f32x4 __attribute__((ext_vector_type(4)));

// bucket list offsets: OFF[s] = 64 * sum_{s'<s} ceil(512/(s'+1))  (worst-case capacities)
__device__ const int d_OFF[12] = {0,32768,49152,60096,68288,74880,80384,85120,89216,92864,96192,99200};

__device__ __forceinline__ float sigf(float x) { return 1.0f / (1.0f + __expf(-x)); }
__device__ __forceinline__ float tanh_(float x) {
  float e = __expf(-2.0f * fabsf(x));
  float r = (1.0f - e) / (1.0f + e);
  return copysignf(r, x);
}
__device__ __forceinline__ f32x4 mfma16(f16x8 a, f16x8 b, f32x4 c) {
  return __builtin_amdgcn_mfma_f32_16x16x32_f16(a, b, c, 0, 0, 0);
}

// ---------------- generic f32 -> f16 cast (vectorized) ----------------
__global__ __launch_bounds__(256) void cast_f16(const float* __restrict__ s, f16* __restrict__ d, int n4) {
  int i = blockIdx.x * 256 + threadIdx.x;
  int stride = gridDim.x * 256;
  for (; i < n4; i += stride) {
    float4 v = ((const float4*)s)[i];
    f16x4 o = { (f16)v.x, (f16)v.y, (f16)v.z, (f16)v.w };
    ((f16x4*)d)[i] = o;
  }
}

__global__ __launch_bounds__(256) void bias_add(const float* __restrict__ a, const float* __restrict__ b,
                                                float* __restrict__ o, int n) {
  int i = blockIdx.x * 256 + threadIdx.x;
  if (i < n) o[i] = a[i] + b[i];
}

// ---------------- segment bucket lists (shared by both layers; same mask) ----------------
__global__ __launch_bounds__(512) void build_lists(const float* __restrict__ mask,
    int* __restrict__ counts, int* __restrict__ lists,
    int* __restrict__ tailcnt, int* __restrict__ taillist) {
  int b = blockIdx.x, t = threadIdx.x;
  __shared__ float sm[512];
  sm[t] = mask[b*TT + t];
  __syncthreads();
  int run = 0;
  for (int j = 1; j <= 12; ++j) {
    if (t - j < 0) break;
    if (sm[t - j] != 0.0f) run++; else break;
  }
  bool tail = (run >= 12);
  if (!tail) {
    int slot = atomicAdd(&counts[run], 1);
    lists[d_OFF[run] + slot] = b*TT + t;
  }
  // ordered (by t) per-batch list of tail positions via block scan
  unsigned long long bal = __ballot(tail);
  int lane = t & 63, w = t >> 6;
  int wpre = __popcll(bal & ((1ull << lane) - 1ull));
  __shared__ int wsum[8];
  if (lane == 0) wsum[w] = __popcll(bal);
  __syncthreads();
  int base = 0;
  for (int i = 0; i < w; ++i) base += wsum[i];
  if (tail) taillist[b*TT + base + wpre] = t;
  if (t == 0) {
    int tot = 0;
    for (int i = 0; i < 8; ++i) tot += wsum[i];
    tailcnt[b] = tot;
  }
}

// ---------------- projection GEMM: C[M][2048] = A[M][K] @ W[2048][K]^T + bias ----------------
// 128x128 tile, BK=64, 4 waves (2x2), f16 MFMA 16x16x32, XOR-swizzled LDS.
__global__ __launch_bounds__(256) void proj_gemm(const f16* __restrict__ A,
    const f16* __restrict__ W, const float* __restrict__ bias,
    f16* __restrict__ C, int K) {
  __shared__ __align__(16) f16 As[128*64];
  __shared__ __align__(16) f16 Bs[128*64];
  const int m0 = blockIdx.x * 128;
  const int n0 = blockIdx.y * 128;
  const int tid = threadIdx.x;
  const int lane = tid & 63;
  const int w = tid >> 6;
  const int wm = (w >> 1) * 64;
  const int wn = (w & 1) * 64;
  const int srow = tid >> 3;  // staging: 32 rows per round, 8 chunks of 16B per row
  const int sc = tid & 7;
  f32x4 acc[4][4] = {};
  for (int k0 = 0; k0 < K; k0 += 64) {
    float4 av[4], bv[4];
#pragma unroll
    for (int r = 0; r < 4; ++r) {
      int row = srow + r*32;
      av[r] = *(const float4*)(A + (size_t)(m0 + row)*K + k0 + sc*8);
      bv[r] = *(const float4*)(W + (size_t)(n0 + row)*K + k0 + sc*8);
    }
    __syncthreads();
#pragma unroll
    for (int r = 0; r < 4; ++r) {
      int row = srow + r*32;
      int cs = sc ^ (row & 7);
      *(float4*)(As + row*64 + cs*8) = av[r];
      *(float4*)(Bs + row*64 + cs*8) = bv[r];
    }
    __syncthreads();
#pragma unroll
    for (int ks = 0; ks < 2; ++ks) {
      int kc = ks*4 + (lane >> 4);
      f16x8 af[4], bf[4];
#pragma unroll
      for (int mi = 0; mi < 4; ++mi) {
        int row = wm + mi*16 + (lane & 15);
        af[mi] = *(const f16x8*)(As + row*64 + ((kc ^ (row & 7))*8));
      }
#pragma unroll
      for (int ni = 0; ni < 4; ++ni) {
        int row = wn + ni*16 + (lane & 15);
        bf[ni] = *(const f16x8*)(Bs + row*64 + ((kc ^ (row & 7))*8));
      }
#pragma unroll
      for (int mi = 0; mi < 4; ++mi)
#pragma unroll
        for (int ni = 0; ni < 4; ++ni)
          acc[mi][ni] = mfma16(af[mi], bf[ni], acc[mi][ni]);
    }
  }
  const int rq = lane >> 4, cl = lane & 15;
#pragma unroll
  for (int ni = 0; ni < 4; ++ni) {
    int gc = n0 + wn + ni*16 + cl;
    float bb = bias[gc];
#pragma unroll
    for (int mi = 0; mi < 4; ++mi)
#pragma unroll
      for (int r = 0; r < 4; ++r) {
        int gr = m0 + wm + mi*16 + rq*4 + r;
        C[(size_t)gr*NG + gc] = (f16)(acc[mi][ni][r] + bb);
      }
  }
}

// ---------------- bucket 0: segment starts (h_prev = c_prev = 0) ----------------
__global__ __launch_bounds__(512) void lstm_step0(const f16* __restrict__ G,
    f16* __restrict__ HS, f16* __restrict__ CS, const float* __restrict__ mask,
    const int* __restrict__ counts, const int* __restrict__ lists) {
  int i = blockIdx.x;
  if (i >= counts[0]) return;
  int row = lists[i];
  int j = threadIdx.x;
  size_t gb = (size_t)row * NG;
  float gi = (float)G[gb + j];
  float gg = (float)G[gb + 1024 + j];
  float go = (float)G[gb + 1536 + j];
  float m = mask[row];
  float c = sigf(gi) * tanh_(gg);
  float h = sigf(go) * tanh_(c);
  h *= m; c *= m;
  HS[(size_t)row*HH + j] = (f16)h;
  CS[(size_t)row*HH + j] = (f16)c;
}

// ---------------- bucket s (1..11): gathered-row MFMA step ----------------
// block: 32 gathered rows x 128 h-cols (blockIdx.y splits 512 h-cols into 4).
// wave w owns h-cols [jt, jt+16) and all 4 gate quadrants for them -> activation wave-local.
__global__ __launch_bounds__(512) void lstm_step(const f16* __restrict__ Wh,
    const f16* __restrict__ G, f16* __restrict__ HS, f16* __restrict__ CS,
    const float* __restrict__ mask, const int* __restrict__ counts,
    const int* __restrict__ lists, int s) {
  const int cnt = counts[s];
  const int mbase = blockIdx.x * 32;
  if (mbase >= cnt) return;
  const int* lst = lists + d_OFF[s];
  const int tid = threadIdx.x;
  const int lane = tid & 63;
  const int w = tid >> 6;
  const int jt = blockIdx.y * 128 + w * 16;
  __shared__ int ridx[32];
  __shared__ float rmk[32];
  if (tid < 32) {
    int i = mbase + tid;
    int r = (i < cnt) ? lst[i] : -1;
    ridx[tid] = r;
    rmk[tid] = (r >= 0) ? mask[r] : 0.0f;
  }
  __syncthreads();
  const int cl = lane & 15, kq = lane >> 4;
  int am0 = ridx[cl], am1 = ridx[16 + cl];
  const f16* a0p = HS + (size_t)((am0 > 0) ? (am0 - 1) : 0) * HH + kq * 8;
  const f16* a1p = HS + (size_t)((am1 > 0) ? (am1 - 1) : 0) * HH + kq * 8;
  const f16* b0p = Wh + (size_t)(jt + cl) * HH + kq * 8;
  const f16* b1p = b0p + (size_t)512 * HH;
  const f16* b2p = b0p + (size_t)1024 * HH;
  const f16* b3p = b0p + (size_t)1536 * HH;
  f32x4 acc[2][4] = {};
  for (int ks = 0; ks < 16; ++ks) {
    f16x8 a0 = *(const f16x8*)(a0p + ks*32);
    f16x8 a1 = *(const f16x8*)(a1p + ks*32);
    f16x8 b0 = *(const f16x8*)(b0p + ks*32);
    f16x8 b1 = *(const f16x8*)(b1p + ks*32);
    f16x8 b2 = *(const f16x8*)(b2p + ks*32);
    f16x8 b3 = *(const f16x8*)(b3p + ks*32);
    acc[0][0] = mfma16(a0, b0, acc[0][0]);
    acc[1][0] = mfma16(a1, b0, acc[1][0]);
    acc[0][1] = mfma16(a0, b1, acc[0][1]);
    acc[1][1] = mfma16(a1, b1, acc[1][1]);
    acc[0][2] = mfma16(a0, b2, acc[0][2]);
    acc[1][2] = mfma16(a1, b2, acc[1][2]);
    acc[0][3] = mfma16(a0, b3, acc[0][3]);
    acc[1][3] = mfma16(a1, b3, acc[1][3]);
  }
  const int j = jt + cl;
#pragma unroll
  for (int mi = 0; mi < 2; ++mi) {
#pragma unroll
    for (int r = 0; r < 4; ++r) {
      int slot = mi*16 + kq*4 + r;
      int row = ridx[slot];
      if (row >= 0) {
        size_t gb = (size_t)row * NG;
        float gi = acc[mi][0][r] + (float)G[gb + j];
        float gf = acc[mi][1][r] + (float)G[gb + 512 + j];
        float gg = acc[mi][2][r] + (float)G[gb + 1024 + j];
        float go = acc[mi][3][r] + (float)G[gb + 1536 + j];
        float cp = (float)CS[(size_t)(row - 1)*HH + j];
        float c = sigf(gf)*cp + sigf(gi)*tanh_(gg);
        float h = sigf(go)*tanh_(c);
        float m = rmk[slot];
        h *= m; c *= m;
        HS[(size_t)row*HH + j] = (f16)h;
        CS[(size_t)row*HH + j] = (f16)c;
      }
    }
  }
}

// ---------------- tail: positions with s>=12, sequential per batch (rare) ----------------
__global__ __launch_bounds__(1024) void lstm_tail(const f16* __restrict__ Wh,
    const f16* __restrict__ G, f16* __restrict__ HS, f16* __restrict__ CS,
    const float* __restrict__ mask, const int* __restrict__ tailcnt,
    const int* __restrict__ taillist) {
  int b = blockIdx.x;
  int n = tailcnt[b];
  if (n == 0) return;
  int tid = threadIdx.x;
  __shared__ __align__(4) f16 hsh[512];
  __shared__ float gsh[2048];
  for (int i = 0; i < n; ++i) {
    int t = taillist[b*TT + i];
    size_t row = (size_t)b*TT + t;
    if (tid < 256)
      ((uint32_t*)hsh)[tid] = ((const uint32_t*)(HS + (row - 1)*HH))[tid];
    __syncthreads();
#pragma unroll
    for (int rep = 0; rep < 2; ++rep) {
      int o = tid + rep*1024;
      float acc = (float)G[row*NG + o];
      const f16x8* wr = (const f16x8*)(Wh + (size_t)o*HH);
      const f16x2* hp = (const f16x2*)hsh;
#pragma unroll 4
      for (int k8 = 0; k8 < 64; ++k8) {
        f16x8 wv = wr[k8];
        f16x2 p0 = {wv[0], wv[1]}, p1 = {wv[2], wv[3]}, p2 = {wv[4], wv[5]}, p3 = {wv[6], wv[7]};
        acc = __builtin_amdgcn_fdot2(p0, hp[k8*4+0], acc, false);
        acc = __builtin_amdgcn_fdot2(p1, hp[k8*4+1], acc, false);
        acc = __builtin_amdgcn_fdot2(p2, hp[k8*4+2], acc, false);
        acc = __builtin_amdgcn_fdot2(p3, hp[k8*4+3], acc, false);
      }
      gsh[o] = acc;
    }
    __syncthreads();
    if (tid < 512) {
      int j = tid;
      float cp = (float)CS[(row - 1)*HH + j];
      float c = sigf(gsh[512 + j])*cp + sigf(gsh[j])*tanh_(gsh[1024 + j]);
      float h = sigf(gsh[1536 + j])*tanh_(c);
      float m = mask[row];
      h *= m; c *= m;
      HS[row*HH + j] = (f16)h;
      CS[row*HH + j] = (f16)c;
    }
    __syncthreads();
  }
}

// ---------------- relu + layernorm over H=512 (one row per block) ----------------
__global__ __launch_bounds__(512) void ln_relu(const f16* __restrict__ in,
    const float* __restrict__ g, const float* __restrict__ be,
    f16* __restrict__ out, int nrows) {
  int row = blockIdx.x;
  if (row >= nrows) return;
  int j = threadIdx.x;
  float x = fmaxf((float)in[(size_t)row*HH + j], 0.0f);
  float s1 = x, s2 = x*x;
  for (int o = 32; o > 0; o >>= 1) { s1 += __shfl_down(s1, o); s2 += __shfl_down(s2, o); }
  __shared__ float a1[8], a2[8];
  int w = j >> 6;
  if ((j & 63) == 0) { a1[w] = s1; a2[w] = s2; }
  __syncthreads();
  if (j == 0) {
    float t1 = 0.f, t2 = 0.f;
    for (int i = 0; i < 8; ++i) { t1 += a1[i]; t2 += a2[i]; }
    a1[0] = t1; a2[0] = t2;
  }
  __syncthreads();
  float mu = a1[0] * (1.0f/512.0f);
  float var = a2[0] * (1.0f/512.0f) - mu*mu;
  float y = (x - mu) * rsqrtf(var + 1e-5f) * g[j] + be[j];
  out[(size_t)row*HH + j] = (f16)y;
}

// layernorm of the final (t=T-1) hidden state, f32 output
__global__ __launch_bounds__(512) void ln_last(const f16* __restrict__ HS,
    const float* __restrict__ g, const float* __restrict__ be, float* __restrict__ out) {
  int b = blockIdx.x;
  int j = threadIdx.x;
  float x = fmaxf((float)HS[((size_t)b*TT + (TT-1))*HH + j], 0.0f);
  float s1 = x, s2 = x*x;
  for (int o = 32; o > 0; o >>= 1) { s1 += __shfl_down(s1, o); s2 += __shfl_down(s2, o); }
  __shared__ float a1[8], a2[8];
  int w = j >> 6;
  if ((j & 63) == 0) { a1[w] = s1; a2[w] = s2; }
  __syncthreads();
  if (j == 0) {
    float t1 = 0.f, t2 = 0.f;
    for (int i = 0; i < 8; ++i) { t1 += a1[i]; t2 += a2[i]; }
    a1[0] = t1; a2[0] = t2;
  }
  __syncthreads();
  float mu = a1[0] * (1.0f/512.0f);
  float var = a2[0] * (1.0f/512.0f) - mu*mu;
  float y = (x - mu) * rsqrtf(var + 1e-5f) * g[j] + be[j];
  out[b*HH + j] = y;
}

// ---------------- final classifier: out[64][1000] = hf @ fcW^T + fcb ----------------
__global__ __launch_bounds__(256) void fc_kernel(const float* __restrict__ hf,
    const float* __restrict__ W, const float* __restrict__ bias, float* __restrict__ out) {
  int b = blockIdx.y;
  int c = blockIdx.x * 256 + threadIdx.x;
  __shared__ float hsh[512];
  hsh[threadIdx.x] = hf[b*HH + threadIdx.x];
  hsh[threadIdx.x + 256] = hf[b*HH + 256 + threadIdx.x];
  __syncthreads();
  if (c < NCLS) {
    const float4* wr = (const float4*)(W + (size_t)c*HH);
    float acc = bias[c];
#pragma unroll 4
    for (int k4 = 0; k4 < 128; ++k4) {
      float4 wv = wr[k4];
      acc += wv.x*hsh[k4*4] + wv.y*hsh[k4*4+1] + wv.z*hsh[k4*4+2] + wv.w*hsh[k4*4+3];
    }
    out[b*NCLS + c] = acc;
  }
}

extern "C" void kernel_launch(void* const* d_in, const int* in_sizes, int n_in,
                              void* d_out, int out_size, void* d_ws, size_t ws_size,
                              hipStream_t stream) {
  (void)in_sizes; (void)n_in; (void)out_size;
  const float* x    = (const float*)d_in[0];
  const float* mask = (const float*)d_in[1];
  const float* Wih0 = (const float*)d_in[2];
  const float* Whh0 = (const float*)d_in[3];
  const float* bih0 = (const float*)d_in[4];
  const float* bhh0 = (const float*)d_in[5];
  const float* g0   = (const float*)d_in[6];
  const float* be0  = (const float*)d_in[7];
  const float* Wih1 = (const float*)d_in[8];
  const float* Whh1 = (const float*)d_in[9];
  const float* bih1 = (const float*)d_in[10];
  const float* bhh1 = (const float*)d_in[11];
  const float* g1   = (const float*)d_in[12];
  const float* be1  = (const float*)d_in[13];
  const float* fcW  = (const float*)d_in[14];
  const float* fcb  = (const float*)d_in[15];
  float* out = (float*)d_out;

  char* ws = (char*)d_ws;
  size_t off = 0;
  auto alloc = [&](size_t bytes) { size_t o = off; off += (bytes + 255) & ~(size_t)255; return o; };
  f16* G      = (f16*)(ws + alloc((size_t)BT*NG*2));      // 128MB, reused for both layers
  f16* HS     = (f16*)(ws + alloc((size_t)BT*HH*2));      // 32MB, reused
  f16* CS     = (f16*)(ws + alloc((size_t)BT*HH*2));      // 32MB, reused
  f16* H0LN   = (f16*)(ws + alloc((size_t)BT*HH*2));      // 32MB; first holds x-f16, later LN(layer0)
  f16* W16ih0 = (f16*)(ws + alloc((size_t)NG*DD*2));
  f16* W16hh0 = (f16*)(ws + alloc((size_t)NG*HH*2));
  f16* W16ih1 = (f16*)(ws + alloc((size_t)NG*HH*2));
  f16* W16hh1 = (f16*)(ws + alloc((size_t)NG*HH*2));
  float* bias0 = (float*)(ws + alloc(NG*4));
  float* bias1 = (float*)(ws + alloc(NG*4));
  int* counts  = (int*)(ws + alloc(128*4));               // counts[0..11] + tailcnt[64]
  int* tailcnt = counts + 64;
  int* lists   = (int*)(ws + alloc(101952*4));
  int* taillist= (int*)(ws + alloc((size_t)BT*4));
  float* hf    = (float*)(ws + alloc((size_t)BB*HH*4));
  if (ws_size < off) return;  // workspace too small -> visible validation failure

  f16* AX = H0LN;  // x cast region (16MB < 32MB), consumed by proj0 before H0LN written

  hipMemsetAsync(counts, 0, 128*4, stream);
  cast_f16<<<dim3(512), dim3(256), 0, stream>>>(x, AX, BT*DD/4);
  cast_f16<<<dim3(256), dim3(256), 0, stream>>>(Wih0, W16ih0, NG*DD/4);
  cast_f16<<<dim3(256), dim3(256), 0, stream>>>(Whh0, W16hh0, NG*HH/4);
  cast_f16<<<dim3(256), dim3(256), 0, stream>>>(Wih1, W16ih1, NG*HH/4);
  cast_f16<<<dim3(256), dim3(256), 0, stream>>>(Whh1, W16hh1, NG*HH/4);
  bias_add<<<dim3(8), dim3(256), 0, stream>>>(bih0, bhh0, bias0, NG);
  bias_add<<<dim3(8), dim3(256), 0, stream>>>(bih1, bhh1, bias1, NG);
  build_lists<<<dim3(BB), dim3(512), 0, stream>>>(mask, counts, lists, tailcnt, taillist);

  // ---- layer 0 ----
  proj_gemm<<<dim3(BT/128, NG/128), dim3(256), 0, stream>>>(AX, W16ih0, bias0, G, DD);
  lstm_step0<<<dim3(BT), dim3(512), 0, stream>>>(G, HS, CS, mask, counts, lists);
  for (int s = 1; s < 12; ++s) {
    int gx = 2 * ((TT + s) / (s + 1));  // 2*ceil(512/(s+1)) blocks of 32 rows (worst case)
    lstm_step<<<dim3(gx, 4), dim3(512), 0, stream>>>(W16hh0, G, HS, CS, mask, counts, lists, s);
  }
  lstm_tail<<<dim3(BB), dim3(1024), 0, stream>>>(W16hh0, G, HS, CS, mask, tailcnt, taillist);
  ln_relu<<<dim3(BT), dim3(512), 0, stream>>>(HS, g0, be0, H0LN, BT);

  // ---- layer 1 ----
  proj_gemm<<<dim3(BT/128, NG/128), dim3(256), 0, stream>>>(H0LN, W16ih1, bias1, G, HH);
  lstm_step0<<<dim3(BT), dim3(512), 0, stream>>>(G, HS, CS, mask, counts, lists);
  for (int s = 1; s < 12; ++s) {
    int gx = 2 * ((TT + s) / (s + 1));
    lstm_step<<<dim3(gx, 4), dim3(512), 0, stream>>>(W16hh1, G, HS, CS, mask, counts, lists, s);
  }
  lstm_tail<<<dim3(BB), dim3(1024), 0, stream>>>(W16hh1, G, HS, CS, mask, tailcnt, taillist);

  // ---- head ----
  ln_last<<<dim3(BB), dim3(512), 0, stream>>>(HS, g1, be1, hf);
  fc_kernel<<<dim3(4, BB), dim3(256), 0, stream>>>(hf, fcW, fcb, out);
}